// Round 2
// baseline (208.074 us; speedup 1.0000x reference)
//
#include <hip/hip_runtime.h>

// PatchEncoder fused kernel, round 5 (resubmit — R1 bench was an infra
// failure: "MI355X container failed twice", no kernel signal).
// out[b, (h/16)*32 + w/16, (h%16)*48 + (w%16)*3 + c]
//   = conv3x3_SAME(X)[b,h,w,c] + bias[c]
//     + pos_emb[(h/4)*128 + (w/4), (h%4)*12 + (w%4)*3 + c]
//
// R4 (LDS + global_load_lds DMA) sat at 69 us/dispatch with every pipe
// under 35% and 9.6M LDS bank-conflict cycles (~23% of CU-cycles): the
// block-serial DMA -> vmcnt(0)-drain barrier -> compute structure exposes
// an HBM round trip per block and the "conflict-free" b128 stride pattern
// is not conflict-free in HW.
//
// R5: no LDS at all. The only data reuse is 3x vertical within a block,
// which L1/L2 absorb (Common-mistake #7: don't stage what cache-fits).
// Each thread: 15 aligned global_load_dwordx4 (3 rows x 20 floats),
// 324 FMAs from registers, 3 float4 stores. No barriers, no fixup phase,
// no DMA queue -> pure TLP latency hiding at ~8 waves/SIMD.
// Window base (3*w0 - 4 + 12*g) is 0 mod 4 floats -> all loads 16B aligned.
// Edge blocks (~30%) take a templated path: per-load pointer clamps
// (only j=0 can underflow / j=4 overflow for row-valid lanes) + register
// zeroing, semantically identical to R4's LDS fixups.

#define BATCH 32
#define IMH 512
#define IMW 512

template <bool EDGE>
__device__ __forceinline__ void conv_rows(
    float acc[12], const float wk[81],
    const float* __restrict__ Xb, const float* xlo, const float* xhi,
    int h0, int r, int w0, int g, bool zlo, bool zhi)
{
#pragma unroll
    for (int dr = 0; dr < 3; ++dr) {
        const int h = h0 + r - 1 + dr;
        const float* gp = Xb + (long)h * (IMW * 3) + (3 * w0 - 4) + 12 * g;
        float s[20];
        if (EDGE) {
            const bool rowValid = ((unsigned)h < IMH);
            if (!rowValid) {
#pragma unroll
                for (int k = 0; k < 20; ++k) s[k] = 0.0f;
            } else {
#pragma unroll
                for (int j = 0; j < 5; ++j) {
                    const float* p = gp + 4 * j;
                    if (j == 0) p = (p < xlo) ? xlo : p;   // lEdge g==0 underflow (16B)
                    if (j == 4) p = (p > xhi) ? xhi : p;   // rEdge g==15 overflow (16B)
                    *(float4*)&s[4 * j] = *(const float4*)p;
                }
                if (zlo) { s[1] = 0.0f; s[2] = 0.0f; s[3] = 0.0f; }     // col w=-1
                if (zhi) { s[16] = 0.0f; s[17] = 0.0f; s[18] = 0.0f; }  // col w=512
            }
        } else {
#pragma unroll
            for (int j = 0; j < 5; ++j)
                *(float4*)&s[4 * j] = *(const float4*)(gp + 4 * j);  // global_load_dwordx4
        }

#pragma unroll
        for (int dc = 0; dc < 3; ++dc)
#pragma unroll
            for (int ci = 0; ci < 3; ++ci) {
                const float* wp = &wk[((dr * 3 + dc) * 3 + ci) * 3];
#pragma unroll
                for (int i = 0; i < 4; ++i) {
                    const float x = s[3 * (i + dc) + ci + 1];
                    acc[i * 3 + 0] = fmaf(x, wp[0], acc[i * 3 + 0]);
                    acc[i * 3 + 1] = fmaf(x, wp[1], acc[i * 3 + 1]);
                    acc[i * 3 + 2] = fmaf(x, wp[2], acc[i * 3 + 2]);
                }
            }
    }
}

__global__ __launch_bounds__(256, 4) void patch_enc_kernel(
    const float* __restrict__ X,     // [B,H,W,3] NHWC
    const float* __restrict__ Kw,    // [3,3,3,3] HWIO
    const float* __restrict__ bias,  // [3]
    const float* __restrict__ pos,   // [16384,48]
    float* __restrict__ out)         // [B,1024,768]
{
    const int tid = threadIdx.x;
    const int w0  = blockIdx.x * 64;
    const int h0  = blockIdx.y * 16;
    const int b   = blockIdx.z;

    const int g = tid & 15;          // col group: 4 pixels = 12 floats
    const int r = tid >> 4;          // output row within tile

    const bool lEdge = (w0 == 0);
    const bool rEdge = (w0 == IMW - 64);
    const bool tEdge = (h0 == 0);
    const bool bEdge = (h0 == IMH - 16);
    const bool edge  = lEdge | rEdge | tEdge | bEdge;

    const float* Xb  = X + (size_t)b * (IMH * IMW * 3);
    const float* xlo = X;
    const float* xhi = X + (size_t)BATCH * IMH * IMW * 3 - 4;

    // uniform weight reads -> s_load into SGPRs
    float wk[81];
#pragma unroll
    for (int i = 0; i < 81; ++i) wk[i] = Kw[i];
    const float bs0 = bias[0], bs1 = bias[1], bs2 = bias[2];

    float acc[12];
#pragma unroll
    for (int i = 0; i < 12; ++i) acc[i] = 0.0f;

    if (edge) {
        conv_rows<true>(acc, wk, Xb, xlo, xhi, h0, r, w0, g,
                        lEdge && (g == 0), rEdge && (g == 15));
    } else {
        conv_rows<false>(acc, wk, Xb, xlo, xhi, h0, r, w0, g, false, false);
    }

    // ---- epilogue: bias + pos_emb + permuted store ----
    const int hg  = h0 + r;
    const int wg0 = w0 + (g << 2);
    const int n   = (hg >> 2) * 128 + (wg0 >> 2);
    const float* pp = pos + (size_t)n * 48 + (hg & 3) * 12;   // 16B aligned
    const float4 p0 = ((const float4*)pp)[0];
    const float4 p1 = ((const float4*)pp)[1];
    const float4 p2 = ((const float4*)pp)[2];

    float v[12];
    v[0]  = acc[0]  + bs0 + p0.x;  v[1]  = acc[1]  + bs1 + p0.y;
    v[2]  = acc[2]  + bs2 + p0.z;  v[3]  = acc[3]  + bs0 + p0.w;
    v[4]  = acc[4]  + bs1 + p1.x;  v[5]  = acc[5]  + bs2 + p1.y;
    v[6]  = acc[6]  + bs0 + p1.z;  v[7]  = acc[7]  + bs1 + p1.w;
    v[8]  = acc[8]  + bs2 + p2.x;  v[9]  = acc[9]  + bs0 + p2.y;
    v[10] = acc[10] + bs1 + p2.z;  v[11] = acc[11] + bs2 + p2.w;

    const int np = (hg >> 4) * 32 + (wg0 >> 4);
    float* op = out + (size_t)b * 786432 + (size_t)np * 768
                    + (hg & 15) * 48 + ((wg0 >> 2) & 3) * 12;
    ((float4*)op)[0] = make_float4(v[0], v[1], v[2],  v[3]);
    ((float4*)op)[1] = make_float4(v[4], v[5], v[6],  v[7]);
    ((float4*)op)[2] = make_float4(v[8], v[9], v[10], v[11]);
}

extern "C" void kernel_launch(void* const* d_in, const int* in_sizes, int n_in,
                              void* d_out, int out_size, void* d_ws, size_t ws_size,
                              hipStream_t stream) {
    const float* X    = (const float*)d_in[0];
    const float* Kw   = (const float*)d_in[1];
    const float* bias = (const float*)d_in[2];
    const float* pos  = (const float*)d_in[3];
    float* out = (float*)d_out;

    dim3 grid(IMW / 64, IMH / 16, BATCH);   // 8 x 32 x 32 = 8192 blocks
    patch_enc_kernel<<<grid, 256, 0, stream>>>(X, Kw, bias, pos, out);
}

// Round 3
// 187.233 us; speedup vs baseline: 1.1113x; 1.1113x over previous
//
#include <hip/hip_runtime.h>

// PatchEncoder fused kernel, round 6.
// out[b, (h/16)*32 + w/16, (h%16)*48 + (w%16)*3 + c]
//   = conv3x3_SAME(X)[b,h,w,c] + bias[c]
//     + pos_emb[(h/4)*128 + (w/4), (h%4)*12 + (w%4)*3 + c]
//
// History: R4 (LDS DMA staging, 1 row/thread, scattered stores) = 69 us;
// R5 (no LDS, per-thread windowed loads) = 86 us. R5 proved the load side
// must stay contiguous-per-instruction (scattered 48B-stride lanes cost
// ~50 cache-line touches per vmem inst vs 16 for the DMA path), while its
// zero-conflict result isolated R4's 9.6M conflict cycles to the LDS phase.
//
// R6 = R4 staging + three fixes:
//  1. 2 output rows/thread (tile 64x32): LDS reads -33%, addr/epilogue
//     VALU amortized 2x, one shared pos row per thread (96B contiguous).
//  2. Output staged in LDS (buffer reused after compute), then stored as
//     two contiguous 12KB regions: 6 x 1KB/wave coalesced dwordx4 stores
//     instead of 3 scattered 48B-unit stores.
//  3. DMA input staging + b128 window reads unchanged.

#define BATCH 32
#define IMH 512
#define IMW 512
#define RSF 260            // LDS input row stride, floats
#define NROW 34            // 32 rows + 2 halo
#define TILEW 64
#define TILEH 32

__device__ __forceinline__ void dma16(const float* g, float* l) {
    __builtin_amdgcn_global_load_lds(
        (const __attribute__((address_space(1))) void*)g,
        (__attribute__((address_space(3))) void*)l,
        16, 0, 0);
}

__global__ __launch_bounds__(256, 4) void patch_enc_kernel(
    const float* __restrict__ X,     // [B,H,W,3] NHWC
    const float* __restrict__ Kw,    // [3,3,3,3] HWIO
    const float* __restrict__ bias,  // [3]
    const float* __restrict__ pos,   // [16384,48]
    float* __restrict__ out)         // [B,1024,768]
{
    __shared__ float lds[NROW * RSF];   // 8840 floats = 35.4 KB (>= 6144 out-stage)

    const int tid = threadIdx.x;
    const int w0  = blockIdx.x * TILEW;
    const int h0  = blockIdx.y * TILEH;
    const int b   = blockIdx.z;

    const bool lEdge = (w0 == 0);
    const bool rEdge = (w0 == IMW - TILEW);
    const bool tEdge = (h0 == 0);
    const bool bEdge = (h0 == IMH - TILEH);

    const float* Xb = X + (size_t)b * (IMH * IMW * 3);

    // ---- async-stage 34 halo rows, contiguous 1KB per wave-inst ----
    {
        const int lane = tid & 63;
        const int wv   = tid >> 6;
        const float* xlo = X;
        const float* xhi = X + (size_t)BATCH * IMH * IMW * 3 - 4;  // last 16B start
        for (int row = wv; row < NROW; row += 4) {
            const int h = h0 - 1 + row;
            if ((unsigned)h < IMH) {                // wave-uniform branch
                const float* gp = Xb + (size_t)h * (IMW * 3) + (3 * w0 - 4) + lane * 4;
                if (lEdge) gp = (gp < xlo) ? xlo : gp;   // cndmask, exec stays full
                if (rEdge) gp = (gp > xhi) ? xhi : gp;
                dma16(gp, &lds[row * RSF]);
            }
        }
    }

    // weights while DMA is in flight: uniform -> s_load -> SGPR operands
    float wk[81];
#pragma unroll
    for (int i = 0; i < 81; ++i) wk[i] = Kw[i];
    const float bs0 = bias[0], bs1 = bias[1], bs2 = bias[2];

    __syncthreads();   // drains vmcnt: all DMA rows landed

    // ---- zero-pad fixups (edge blocks only) ----
    if (tEdge) for (int j = tid; j < RSF; j += 256) lds[j] = 0.0f;                    // h=-1
    if (bEdge) for (int j = tid; j < RSF; j += 256) lds[(NROW - 1) * RSF + j] = 0.0f; // h=512
    if (lEdge && tid < 4 * NROW) lds[(tid >> 2) * RSF + (tid & 3)] = 0.0f;            // col -1
    if (rEdge && tid < 4 * NROW) lds[(tid >> 2) * RSF + 196 + (tid & 3)] = 0.0f;      // col 512
    __syncthreads();

    // ---- compute: thread -> rows {h0+2*r2, +1}, col group g (4 px) ----
    const int g  = tid & 15;
    const int r2 = tid >> 4;

    float acc0[12], acc1[12];
#pragma unroll
    for (int i = 0; i < 12; ++i) { acc0[i] = 0.0f; acc1[i] = 0.0f; }

    // LDS row (2*r2+q): feeds out-row0 with weight-row q (q<=2),
    // out-row1 with weight-row q-1 (q>=1). 4 rows read for 2 computed.
#pragma unroll
    for (int q = 0; q < 4; ++q) {
        const float* bp = &lds[(2 * r2 + q) * RSF + 12 * g];
        float s[20];
#pragma unroll
        for (int j = 0; j < 5; ++j)
            *(float4*)&s[4 * j] = *(const float4*)(bp + 4 * j);   // ds_read_b128
#pragma unroll
        for (int dc = 0; dc < 3; ++dc)
#pragma unroll
        for (int ci = 0; ci < 3; ++ci) {
#pragma unroll
            for (int i = 0; i < 4; ++i) {
                const float x = s[3 * (i + dc) + ci + 1];
                if (q <= 2) {
                    const float* wp = &wk[((q * 3 + dc) * 3 + ci) * 3];
                    acc0[i * 3 + 0] = fmaf(x, wp[0], acc0[i * 3 + 0]);
                    acc0[i * 3 + 1] = fmaf(x, wp[1], acc0[i * 3 + 1]);
                    acc0[i * 3 + 2] = fmaf(x, wp[2], acc0[i * 3 + 2]);
                }
                if (q >= 1) {
                    const float* wp = &wk[(((q - 1) * 3 + dc) * 3 + ci) * 3];
                    acc1[i * 3 + 0] = fmaf(x, wp[0], acc1[i * 3 + 0]);
                    acc1[i * 3 + 1] = fmaf(x, wp[1], acc1[i * 3 + 1]);
                    acc1[i * 3 + 2] = fmaf(x, wp[2], acc1[i * 3 + 2]);
                }
            }
        }
    }

    // ---- bias + pos_emb (rows share n since hg0 even: one 96B load) ----
    const int hg0 = h0 + 2 * r2;
    const int wg0 = w0 + 4 * g;
    const int n   = (hg0 >> 2) * 128 + (wg0 >> 2);
    const float* pp = pos + (size_t)n * 48 + (hg0 & 3) * 12;   // 16B aligned
    float pr[24];
#pragma unroll
    for (int j = 0; j < 6; ++j)
        *(float4*)&pr[4 * j] = *(const float4*)(pp + 4 * j);

    float v0[12], v1[12];
#pragma unroll
    for (int k = 0; k < 12; ++k) {
        const float bsk = (k % 3 == 0) ? bs0 : (k % 3 == 1) ? bs1 : bs2;
        v0[k] = acc0[k] + bsk + pr[k];
        v1[k] = acc1[k] + bsk + pr[12 + k];
    }

    __syncthreads();   // all input-LDS reads done; reuse buffer for out-stage

    // ---- out-stage: permuted scatter into LDS (6144 floats = 8 patches) ----
    {
        const int p    = 4 * (r2 >> 3) + (g >> 2);               // local patch 0..7
        const int off0 = p * 768 + ((2 * r2) & 15) * 48 + (g & 3) * 12;
        *(float4*)&lds[off0 + 0] = make_float4(v0[0], v0[1], v0[2],  v0[3]);
        *(float4*)&lds[off0 + 4] = make_float4(v0[4], v0[5], v0[6],  v0[7]);
        *(float4*)&lds[off0 + 8] = make_float4(v0[8], v0[9], v0[10], v0[11]);
        const int off1 = off0 + 48;
        *(float4*)&lds[off1 + 0] = make_float4(v1[0], v1[1], v1[2],  v1[3]);
        *(float4*)&lds[off1 + 4] = make_float4(v1[4], v1[5], v1[6],  v1[7]);
        *(float4*)&lds[off1 + 8] = make_float4(v1[8], v1[9], v1[10], v1[11]);
    }
    __syncthreads();

    // ---- coalesced store: two contiguous 12KB regions (np0+0..3, np0+32..35) ----
    {
        float* ob = out + (size_t)b * 786432
                  + (size_t)((h0 >> 4) * 32 + (w0 >> 4)) * 768;
#pragma unroll
        for (int c = 0; c < 6; ++c) {
            const int d = 4 * (tid + 256 * c);          // LDS dword index
            const float4 val = *(const float4*)&lds[d];
            const int go = (c < 3) ? d : d + 21504;     // region 1 at np0+32 (+24576-3072)
            *(float4*)(ob + go) = val;
        }
    }
}

extern "C" void kernel_launch(void* const* d_in, const int* in_sizes, int n_in,
                              void* d_out, int out_size, void* d_ws, size_t ws_size,
                              hipStream_t stream) {
    const float* X    = (const float*)d_in[0];
    const float* Kw   = (const float*)d_in[1];
    const float* bias = (const float*)d_in[2];
    const float* pos  = (const float*)d_in[3];
    float* out = (float*)d_out;

    dim3 grid(IMW / TILEW, IMH / TILEH, BATCH);   // 8 x 16 x 32 = 4096 blocks
    patch_enc_kernel<<<grid, 256, 0, stream>>>(X, Kw, bias, pos, out);
}